// Round 1
// baseline (267.426 us; speedup 1.0000x reference)
//
#include <hip/hip_runtime.h>

typedef short short8 __attribute__((ext_vector_type(8)));
typedef float f32x4 __attribute__((ext_vector_type(4)));

#define NV 131072
#define KK 27
#define CH 64

__device__ inline unsigned short f2b(float f) {
    unsigned u = __float_as_uint(f);
    u += 0x7fffu + ((u >> 16) & 1u);   // round-to-nearest-even
    return (unsigned short)(u >> 16);
}

// feat f32 [N,C] -> bf16 bits [N,C]
__global__ void prep_feat(const float* __restrict__ feat, unsigned short* __restrict__ featb) {
    int i = blockIdx.x * blockDim.x + threadIdx.x;       // over N*C/4
    float4 v = reinterpret_cast<const float4*>(feat)[i];
    ushort4 o;
    o.x = f2b(v.x); o.y = f2b(v.y); o.z = f2b(v.z); o.w = f2b(v.w);
    reinterpret_cast<ushort4*>(featb)[i] = o;
}

// W [K][Ci][Co] f32 -> Wt [K][Co][Ci] bf16 (both layers in one launch)
__global__ void prep_w(const float* __restrict__ W1, const float* __restrict__ W2,
                       unsigned short* __restrict__ wt1, unsigned short* __restrict__ wt2) {
    int id = blockIdx.x * blockDim.x + threadIdx.x;      // 2*K*C*C
    const float* W = W1; unsigned short* wt = wt1;
    int e = id;
    if (e >= KK * CH * CH) { e -= KK * CH * CH; W = W2; wt = wt2; }
    int k = e >> 12, o = (e >> 6) & 63, c = e & 63;
    wt[e] = f2b(W[k * CH * CH + c * CH + o]);
}

// One sparse-conv layer. EPI 0: relu -> bf16 out. EPI 1: +resid, relu -> f32 out.
// Block = 256 threads = 4 waves; wave owns 64 rows x 64 cols; block covers 256 rows.
template <int EPI>
__global__ __launch_bounds__(256, 2) void conv_layer(
    const unsigned short* __restrict__ xb,   // [N,C] bf16 input
    const unsigned short* __restrict__ wt,   // [K,Co,Ci] bf16 transposed weights
    const float* __restrict__ bias,          // [C]
    const int* __restrict__ nbr,             // [N,K]
    const float* __restrict__ resid,         // [N,C] f32 (EPI==1)
    unsigned short* __restrict__ outb,       // bf16 out (EPI==0)
    float* __restrict__ outf)                // f32 out (EPI==1)
{
    const int wid  = threadIdx.x >> 6;
    const int lane = threadIdx.x & 63;
    const int lr   = lane & 15;     // row-in-tile (A) / col-in-tile (B,D)
    const int kg   = lane >> 4;     // k-group 0..3
    const int rowbase = blockIdx.x * 256 + wid * 64;

    f32x4 acc[4][4];
    #pragma unroll
    for (int t = 0; t < 4; ++t)
        #pragma unroll
        for (int n = 0; n < 4; ++n)
            acc[t][n] = (f32x4){0.f, 0.f, 0.f, 0.f};

    for (int tap = 0; tap < KK; ++tap) {
        // A fragments: 4 row-tiles x 2 K-chunks, gathered via nbr
        short8 a[4][2];
        #pragma unroll
        for (int t = 0; t < 4; ++t) {
            int idx = nbr[(rowbase + t * 16 + lr) * KK + tap];
            const unsigned short* base = xb + idx * CH + kg * 8;
            a[t][0] = *reinterpret_cast<const short8*>(base);
            a[t][1] = *reinterpret_cast<const short8*>(base + 32);
        }
        // B fragments from transposed W (contiguous 16B per lane), 4 col-tiles
        #pragma unroll
        for (int nt = 0; nt < 4; ++nt) {
            const unsigned short* wbase = wt + tap * CH * CH + (nt * 16 + lr) * CH + kg * 8;
            short8 b0 = *reinterpret_cast<const short8*>(wbase);
            short8 b1 = *reinterpret_cast<const short8*>(wbase + 32);
            #pragma unroll
            for (int t = 0; t < 4; ++t) {
                acc[t][nt] = __builtin_amdgcn_mfma_f32_16x16x32_bf16(a[t][0], b0, acc[t][nt], 0, 0, 0);
                acc[t][nt] = __builtin_amdgcn_mfma_f32_16x16x32_bf16(a[t][1], b1, acc[t][nt], 0, 0, 0);
            }
        }
    }

    // Epilogue. D layout: col = lane&15 (within col-tile), row = kg*4 + reg.
    #pragma unroll
    for (int nt = 0; nt < 4; ++nt) {
        int col = nt * 16 + lr;
        float bv = bias[col];
        #pragma unroll
        for (int t = 0; t < 4; ++t) {
            int row0 = rowbase + t * 16 + kg * 4;
            #pragma unroll
            for (int i = 0; i < 4; ++i) {
                float v = acc[t][nt][i] + bv;
                if (EPI == 0) {
                    v = fmaxf(v, 0.f);
                    outb[(size_t)(row0 + i) * CH + col] = f2b(v);
                } else {
                    v += resid[(size_t)(row0 + i) * CH + col];
                    v = fmaxf(v, 0.f);
                    outf[(size_t)(row0 + i) * CH + col] = v;
                }
            }
        }
    }
}

extern "C" void kernel_launch(void* const* d_in, const int* in_sizes, int n_in,
                              void* d_out, int out_size, void* d_ws, size_t ws_size,
                              hipStream_t stream) {
    const float* feat = (const float*)d_in[0];
    const float* W1   = (const float*)d_in[1];
    const float* b1   = (const float*)d_in[2];
    const float* W2   = (const float*)d_in[3];
    const float* b2   = (const float*)d_in[4];
    const int*   nbr  = (const int*)d_in[5];
    float* out = (float*)d_out;

    char* ws = (char*)d_ws;
    unsigned short* featb = (unsigned short*)ws;                              // 16.78 MB
    unsigned short* hb    = (unsigned short*)(ws + (size_t)NV * CH * 2);      // 16.78 MB
    unsigned short* wt1   = (unsigned short*)(ws + (size_t)NV * CH * 4);      // 216 KB
    unsigned short* wt2   = wt1 + KK * CH * CH;                               // 216 KB

    prep_feat<<<NV * CH / 4 / 256, 256, 0, stream>>>(feat, featb);
    prep_w<<<2 * KK * CH * CH / 256, 256, 0, stream>>>(W1, W2, wt1, wt2);
    conv_layer<0><<<NV / 256, 256, 0, stream>>>(featb, wt1, b1, nbr, nullptr, hb, nullptr);
    conv_layer<1><<<NV / 256, 256, 0, stream>>>(hb, wt2, b2, nbr, feat, nullptr, out);
}